// Round 2
// baseline (447.138 us; speedup 1.0000x reference)
//
#include <hip/hip_runtime.h>
#include <cstddef>

// Problem constants
constexpr int NB = 8;      // batch
constexpr int NV = 6;      // views (scan length)
constexpr int NS = 32;     // stochastic dim S
constexpr int ND = 128;    // deter dim D
constexpr int NH = 128;    // hidden H
constexpr int NOBS = 768;  // obs dim

__device__ __forceinline__ float sigf(float x) { return 1.0f / (1.0f + expf(-x)); }
__device__ __forceinline__ float siluf(float x) { return x / (1.0f + expf(-x)); }

// -------- Kernel 0: mask prep (detect int32 vs byte bool layout) --------
__global__ void prep_mask(const void* cam, float* maskf) {
    if (threadIdx.x != 0 || blockIdx.x != 0) return;
    const int* wi = (const int*)cam;
    bool is_i32 = true;
    for (int i = 0; i < NB * NV; i++) {
        unsigned v = (unsigned)wi[i];
        if (v > 1u) { is_i32 = false; break; }
    }
    const unsigned char* wb = (const unsigned char*)cam;
    for (int b = 0; b < NB; b++)
        for (int v = 0; v < NV; v++) {
            int val = is_i32 ? wi[b * NV + v] : (int)wb[b * NV + v];
            maskf[v * NB + b] = val ? 1.0f : 0.0f;   // mask_T layout (V,B)
        }
}

// -------- Kernel 1: feature means (the HBM-bound part) --------
__global__ __launch_bounds__(256) void reduce_feats(
    const float* __restrict__ sf0, const float* __restrict__ sf1,
    const float* __restrict__ tf0, const float* __restrict__ tf1,
    float* __restrict__ obs, float* __restrict__ tgt)
{
    const int NF0 = NB * NV * 256;  // 12288 channels per tensor
    const int NF1 = NB * NV * 512;  // 24576
    int wid = (blockIdx.x * blockDim.x + threadIdx.x) >> 6;
    int lane = threadIdx.x & 63;

    const float* src;
    float* dst;
    int nvec;
    float inv;
    if (wid < 2 * NF0) {
        bool stu = wid < NF0;
        int jj = stu ? wid : wid - NF0;
        src = (stu ? sf0 : tf0) + (size_t)jj * 2816;   // 32*88
        int b = jj / (NV * 256);
        int r = jj % (NV * 256);
        int v = r >> 8;
        int c = r & 255;
        dst = (stu ? obs : tgt) + ((size_t)(v * NB + b)) * NOBS + c;
        nvec = 704;               // 2816/4
        inv = 1.0f / 2816.0f;
    } else {
        int k = wid - 2 * NF0;
        if (k >= 2 * NF1) return;
        bool stu = k < NF1;
        int jj = stu ? k : k - NF1;
        src = (stu ? sf1 : tf1) + (size_t)jj * 704;    // 16*44
        int b = jj / (NV * 512);
        int r = jj % (NV * 512);
        int v = r >> 9;
        int c = r & 511;
        dst = (stu ? obs : tgt) + ((size_t)(v * NB + b)) * NOBS + 256 + c;
        nvec = 176;               // 704/4
        inv = 1.0f / 704.0f;
    }
    const float4* s4 = (const float4*)src;
    float sum = 0.0f;
    for (int k = lane; k < nvec; k += 64) {
        float4 x = s4[k];
        sum += x.x + x.y + x.z + x.w;
    }
    for (int o = 32; o > 0; o >>= 1) sum += __shfl_down(sum, o);
    if (lane == 0) *dst = sum * inv;
}

// -------- Kernel 2: encoder for all 48 (v,b) rows, 512 threads, split-K --------
__global__ __launch_bounds__(512) void encoder(
    const float* __restrict__ obs,
    const float* __restrict__ w1, const float* __restrict__ b1,
    const float* __restrict__ g, const float* __restrict__ be,
    const float* __restrict__ w2, const float* __restrict__ b2,
    float* __restrict__ obs_embed)
{
    __shared__ float xs[NOBS];
    __shared__ float hs[NH];
    __shared__ float pE[4][NH];
    __shared__ float red[2], red2[2];
    int r = blockIdx.x;       // r = v*NB + b
    int tid = threadIdx.x;    // 0..511
    const float* row = obs + (size_t)r * NOBS;
    for (int i = tid; i < NOBS; i += 512) xs[i] = row[i];
    __syncthreads();

    // layer 1: 128 outs x K=768, 4-way split (192 each)
    {
        int part = tid >> 7, j = tid & 127;
        int k0 = part * 192;
        float a = 0.0f;
        for (int k = k0; k < k0 + 192; k++) a += xs[k] * w1[k * NH + j];
        pE[part][j] = a;
    }
    __syncthreads();

    float a1 = 0.0f;
    if (tid < NH) {
        a1 = b1[tid] + pE[0][tid] + pE[1][tid] + pE[2][tid] + pE[3][tid];
        float v = a1;
        for (int o = 32; o > 0; o >>= 1) v += __shfl_down(v, o);
        if ((tid & 63) == 0) red[tid >> 6] = v;
    }
    __syncthreads();
    if (tid < NH) {
        float mu = (red[0] + red[1]) * (1.0f / 128.0f);
        float d = a1 - mu;
        float dv = d * d;
        for (int o = 32; o > 0; o >>= 1) dv += __shfl_down(dv, o);
        if ((tid & 63) == 0) red2[tid >> 6] = dv;
    }
    __syncthreads();
    if (tid < NH) {
        float mu = (red[0] + red[1]) * (1.0f / 128.0f);
        float var = (red2[0] + red2[1]) * (1.0f / 128.0f);
        float xn = (a1 - mu) * rsqrtf(var + 1e-5f) * g[tid] + be[tid];
        hs[tid] = siluf(xn);
    }
    __syncthreads();

    // layer 2: 128 outs x K=128, 4-way split (32 each)
    {
        int part = tid >> 7, j = tid & 127;
        int k0 = part * 32;
        float a = 0.0f;
        for (int k = k0; k < k0 + 32; k++) a += hs[k] * w2[k * NH + j];
        pE[part][j] = a;
    }
    __syncthreads();
    if (tid < NH) {
        float a = b2[tid] + pE[0][tid] + pE[1][tid] + pE[2][tid] + pE[3][tid];
        obs_embed[(size_t)r * NH + tid] = siluf(a);
    }
}

// -------- Kernel 3: RSSM recurrence only (decoder hoisted out), 1024 thr --------
__global__ __launch_bounds__(1024) void rssm_scan(
    const float* __restrict__ obs_embed,
    const float* __restrict__ maskf,
    const float* __restrict__ eps_prior, const float* __restrict__ eps_post,
    const float* __restrict__ prior_w1, const float* __restrict__ prior_b1,
    const float* __restrict__ prior_w2, const float* __restrict__ prior_b2,
    const float* __restrict__ post_w1, const float* __restrict__ post_b1,
    const float* __restrict__ post_w2, const float* __restrict__ post_b2,
    const float* __restrict__ gru_wih, const float* __restrict__ gru_whh,
    const float* __restrict__ gru_bih, const float* __restrict__ gru_bhh,
    float* __restrict__ deter_all, float* __restrict__ z_all,
    float* __restrict__ kl_out)
{
    int b = blockIdx.x;       // 0..7
    int tid = threadIdx.x;    // 0..1023

    __shared__ float deter[ND], obs_e[NH], t1[NH], t2[NH];
    __shared__ float pmu[NS], plv[NS], qmu[NS], qlv[NS], zsm[NS];
    __shared__ float gi_s[3 * ND];
    __shared__ float pA[4][256];
    __shared__ float pB[8][128];
    __shared__ float pD[2][3 * ND];

    if (tid < ND) deter[tid] = 0.0f;
    __syncthreads();

    for (int t = 0; t < NV; t++) {
        int rb = t * NB + b;
        if (tid < NH) obs_e[tid] = obs_embed[(size_t)rb * NH + tid];
        __syncthreads();

        // Phase A: prior hidden (j<128, K=128, 4-way split) | post hidden (K=256, 4-way)
        {
            int part = tid >> 8, j = tid & 255;
            float a = 0.0f;
            if (j < NH) {
                int k0 = part * 32;
                for (int k = k0; k < k0 + 32; k++) a += deter[k] * prior_w1[k * NH + j];
            } else {
                int jj = j - NH;
                int k0 = part * 64;
                for (int k = k0; k < k0 + 64; k++) {
                    float x = (k < ND) ? deter[k] : obs_e[k - ND];
                    a += x * post_w1[k * NH + jj];
                }
            }
            pA[part][j] = a;
        }
        __syncthreads();
        if (tid < 256) {
            int j = tid;
            float a = pA[0][j] + pA[1][j] + pA[2][j] + pA[3][j];
            if (j < NH) { a += prior_b1[j]; t1[j] = siluf(a); }
            else        { a += post_b1[j - NH]; t2[j - NH] = siluf(a); }
        }
        __syncthreads();

        // Phase B: prior2 (64 outs) | post2 (64 outs), K=128, 8-way split (16 each)
        {
            int part = tid >> 7, j = tid & 127;
            int k0 = part * 16;
            float a = 0.0f;
            if (j < 64) {
                for (int k = k0; k < k0 + 16; k++) a += t1[k] * prior_w2[k * 64 + j];
            } else {
                int jj = j - 64;
                for (int k = k0; k < k0 + 16; k++) a += t2[k] * post_w2[k * 64 + jj];
            }
            pB[part][j] = a;
        }
        __syncthreads();
        if (tid < 128) {
            int j = tid;
            float a = 0.0f;
            for (int p = 0; p < 8; p++) a += pB[p][j];
            if (j < 64) {
                a += prior_b2[j];
                if (j < NS) pmu[j] = a; else plv[j - NS] = a;
            } else {
                int jj = j - 64;
                a += post_b2[jj];
                if (jj < NS) qmu[jj] = a; else qlv[jj - NS] = a;
            }
        }
        __syncthreads();

        // Phase C: z sample + KL (first 32 lanes)
        if (tid < NS) {
            float m = maskf[rb];
            float zp = pmu[tid] + eps_prior[(size_t)rb * NS + tid] * expf(0.5f * plv[tid]);
            float zq = qmu[tid] + eps_post[(size_t)rb * NS + tid] * expf(0.5f * qlv[tid]);
            float z = (m > 0.0f) ? zp : zq;
            zsm[tid] = z;
            z_all[(size_t)rb * NS + tid] = z;
            float vq = fmaxf(expf(qlv[tid]), 1e-5f);
            float vp = fmaxf(expf(plv[tid]), 1e-5f);
            float dm = qmu[tid] - pmu[tid];
            float kle = 0.5f * ((vq + dm * dm) / vp - 1.0f + plv[tid] - qlv[tid]);
            for (int o = 16; o > 0; o >>= 1) kle += __shfl_down(kle, o, 32);
            if (tid == 0) kl_out[rb] = kle;
        }
        __syncthreads();

        // Phase D: gi full (384 outs, K=32) + gh (384 outs, K=128, 2-way split 64)
        if (tid < 3 * ND) {
            float a = gru_bih[tid];
            for (int s = 0; s < NS; s++) a += zsm[s] * gru_wih[s * (3 * ND) + tid];
            gi_s[tid] = a;
        }
        if (tid >= 256) {
            int idx = tid - 256;          // 0..767
            int j = idx % 384;
            int part = idx / 384;         // 0 or 1
            int k0 = part * 64;
            float h = 0.0f;
            for (int k = k0; k < k0 + 64; k++) h += deter[k] * gru_whh[k * (3 * ND) + j];
            pD[part][j] = h;
        }
        __syncthreads();

        // Phase E: reduce gh, GRU update, store deter
        if (tid < ND) {
            int j = tid;
            float hr = gru_bhh[j]           + pD[0][j]           + pD[1][j];
            float hz = gru_bhh[ND + j]      + pD[0][ND + j]      + pD[1][ND + j];
            float hn = gru_bhh[2 * ND + j]  + pD[0][2 * ND + j]  + pD[1][2 * ND + j];
            float r = sigf(gi_s[j] + hr);
            float u = sigf(gi_s[ND + j] + hz);
            float n = tanhf(gi_s[2 * ND + j] + r * hn);
            float dn = (1.0f - u) * n + u * deter[j];
            deter[j] = dn;
            deter_all[(size_t)rb * ND + j] = dn;
        }
        __syncthreads();
    }
}

// -------- Kernel 4: decoder + recon MSE, 48-way parallel --------
__global__ __launch_bounds__(512) void decoder_kernel(
    const float* __restrict__ deter_all, const float* __restrict__ z_all,
    const float* __restrict__ tgt,
    const float* __restrict__ dec_w1, const float* __restrict__ dec_b1,
    const float* __restrict__ dec_w2, const float* __restrict__ dec_b2,
    float* __restrict__ recon_out)
{
    int rb = blockIdx.x;      // 0..47
    int tid = threadIdx.x;    // 0..511
    __shared__ float din[ND + NS];   // 160
    __shared__ float d1[NH];
    __shared__ float p1[4][NH];
    __shared__ float redb[8];

    if (tid < ND) din[tid] = deter_all[(size_t)rb * ND + tid];
    else if (tid < ND + NS) din[tid] = z_all[(size_t)rb * NS + (tid - ND)];
    __syncthreads();

    // dec layer 1: 128 outs x K=160, 4-way split (40 each)
    {
        int part = tid >> 7, j = tid & 127;
        int k0 = part * 40;
        float a = 0.0f;
        for (int k = k0; k < k0 + 40; k++) a += din[k] * dec_w1[k * NH + j];
        p1[part][j] = a;
    }
    __syncthreads();
    if (tid < NH) {
        float a = dec_b1[tid] + p1[0][tid] + p1[1][tid] + p1[2][tid] + p1[3][tid];
        d1[tid] = siluf(a);
    }
    __syncthreads();

    // dec layer 2 + MSE
    float se = 0.0f;
    const float* trow = tgt + (size_t)rb * NOBS;
    for (int o = tid; o < NOBS; o += 512) {
        float a = dec_b2[o];
        for (int i = 0; i < NH; i++) a += d1[i] * dec_w2[i * NOBS + o];
        float df = a - trow[o];
        se += df * df;
    }
    for (int o = 32; o > 0; o >>= 1) se += __shfl_down(se, o);
    if ((tid & 63) == 0) redb[tid >> 6] = se;
    __syncthreads();
    if (tid == 0) {
        float s = 0.0f;
        for (int p = 0; p < 8; p++) s += redb[p];
        recon_out[rb] = s * (1.0f / 768.0f);
    }
}

// -------- Kernel 5: finalize (mask-weighted scalar combine) --------
__global__ void finalize(const float* __restrict__ maskf,
                         const float* __restrict__ recon,
                         const float* __restrict__ kl,
                         float* __restrict__ out)
{
    if (threadIdx.x != 0 || blockIdx.x != 0) return;
    float rl = 0.0f, rs = 0.0f, ka = 0.0f, kn = 0.0f;
    for (int t = 0; t < NV; t++) {
        float ms = 0.0f, rsum = 0.0f, osum = 0.0f, ksum = 0.0f;
        for (int b = 0; b < NB; b++) {
            float m = maskf[t * NB + b];
            ms += m;
            rsum += recon[t * NB + b] * m;
            osum += 1.0f - m;
            ksum += kl[t * NB + b] * (1.0f - m);
        }
        if (ms > 0.0f) { rl += rsum / fmaxf(ms, 1.0f); rs += 1.0f; }
        if (osum > 0.0f) { ka += ksum / fmaxf(osum, 1.0f); kn += 1.0f; }
    }
    out[0] = rl / fmaxf(rs, 1.0f);
    out[1] = (ka / fmaxf(kn, 1.0f)) * 1e-4f;
}

extern "C" void kernel_launch(void* const* d_in, const int* in_sizes, int n_in,
                              void* d_out, int out_size, void* d_ws, size_t ws_size,
                              hipStream_t stream) {
    const float* sf0 = (const float*)d_in[0];
    const float* sf1 = (const float*)d_in[1];
    const float* tf0 = (const float*)d_in[2];
    const float* tf1 = (const float*)d_in[3];
    const void*  cam = d_in[4];
    const float* eps_prior = (const float*)d_in[5];
    const float* eps_post  = (const float*)d_in[6];
    const float* enc_w1 = (const float*)d_in[7];
    const float* enc_b1 = (const float*)d_in[8];
    const float* ln_g   = (const float*)d_in[9];
    const float* ln_b   = (const float*)d_in[10];
    const float* enc_w2 = (const float*)d_in[11];
    const float* enc_b2 = (const float*)d_in[12];
    const float* prior_w1 = (const float*)d_in[13];
    const float* prior_b1 = (const float*)d_in[14];
    const float* prior_w2 = (const float*)d_in[15];
    const float* prior_b2 = (const float*)d_in[16];
    const float* post_w1 = (const float*)d_in[17];
    const float* post_b1 = (const float*)d_in[18];
    const float* post_w2 = (const float*)d_in[19];
    const float* post_b2 = (const float*)d_in[20];
    const float* dec_w1 = (const float*)d_in[21];
    const float* dec_b1 = (const float*)d_in[22];
    const float* dec_w2 = (const float*)d_in[23];
    const float* dec_b2 = (const float*)d_in[24];
    const float* gru_wih = (const float*)d_in[25];
    const float* gru_whh = (const float*)d_in[26];
    const float* gru_bih = (const float*)d_in[27];
    const float* gru_bhh = (const float*)d_in[28];

    float* ws = (float*)d_ws;
    float* obs   = ws;                 // 48*768 = 36864
    float* tgt   = ws + 36864;         // 36864
    float* oe    = ws + 73728;         // 48*128 = 6144
    float* maskf = ws + 79872;         // 48
    float* rec   = ws + 79920;         // 48
    float* klv   = ws + 79968;         // 48
    float* deter_all = ws + 80016;     // 48*128 = 6144
    float* z_all     = ws + 86160;     // 48*32  = 1536

    prep_mask<<<1, 64, 0, stream>>>(cam, maskf);
    reduce_feats<<<18432, 256, 0, stream>>>(sf0, sf1, tf0, tf1, obs, tgt);
    encoder<<<48, 512, 0, stream>>>(obs, enc_w1, enc_b1, ln_g, ln_b, enc_w2, enc_b2, oe);
    rssm_scan<<<8, 1024, 0, stream>>>(oe, maskf, eps_prior, eps_post,
                                      prior_w1, prior_b1, prior_w2, prior_b2,
                                      post_w1, post_b1, post_w2, post_b2,
                                      gru_wih, gru_whh, gru_bih, gru_bhh,
                                      deter_all, z_all, klv);
    decoder_kernel<<<48, 512, 0, stream>>>(deter_all, z_all, tgt,
                                           dec_w1, dec_b1, dec_w2, dec_b2, rec);
    finalize<<<1, 64, 0, stream>>>(maskf, rec, klv, (float*)d_out);
}

// Round 3
// 252.659 us; speedup vs baseline: 1.7697x; 1.7697x over previous
//
#include <hip/hip_runtime.h>
#include <cstddef>

// Problem constants
constexpr int NB = 8;      // batch
constexpr int NV = 6;      // views (scan length)
constexpr int NS = 32;     // stochastic dim S
constexpr int ND = 128;    // deter dim D
constexpr int NH = 128;    // hidden H
constexpr int NOBS = 768;  // obs dim

__device__ __forceinline__ float sigf(float x) { return 1.0f / (1.0f + expf(-x)); }
__device__ __forceinline__ float siluf(float x) { return x / (1.0f + expf(-x)); }

// -------- Kernel 0: mask prep (detect int32 vs byte bool layout) --------
__global__ void prep_mask(const void* cam, float* maskf) {
    if (threadIdx.x != 0 || blockIdx.x != 0) return;
    const int* wi = (const int*)cam;
    bool is_i32 = true;
    for (int i = 0; i < NB * NV; i++) {
        unsigned v = (unsigned)wi[i];
        if (v > 1u) { is_i32 = false; break; }
    }
    const unsigned char* wb = (const unsigned char*)cam;
    for (int b = 0; b < NB; b++)
        for (int v = 0; v < NV; v++) {
            int val = is_i32 ? wi[b * NV + v] : (int)wb[b * NV + v];
            maskf[v * NB + b] = val ? 1.0f : 0.0f;   // mask_T layout (V,B)
        }
}

// -------- Kernel 1: feature means (the HBM-bound part) --------
__global__ __launch_bounds__(256) void reduce_feats(
    const float* __restrict__ sf0, const float* __restrict__ sf1,
    const float* __restrict__ tf0, const float* __restrict__ tf1,
    float* __restrict__ obs, float* __restrict__ tgt)
{
    const int NF0 = NB * NV * 256;  // 12288 channels per tensor
    const int NF1 = NB * NV * 512;  // 24576
    int wid = (blockIdx.x * blockDim.x + threadIdx.x) >> 6;
    int lane = threadIdx.x & 63;

    const float* src;
    float* dst;
    int nvec;
    float inv;
    if (wid < 2 * NF0) {
        bool stu = wid < NF0;
        int jj = stu ? wid : wid - NF0;
        src = (stu ? sf0 : tf0) + (size_t)jj * 2816;   // 32*88
        int b = jj / (NV * 256);
        int r = jj % (NV * 256);
        int v = r >> 8;
        int c = r & 255;
        dst = (stu ? obs : tgt) + ((size_t)(v * NB + b)) * NOBS + c;
        nvec = 704;               // 2816/4
        inv = 1.0f / 2816.0f;
    } else {
        int k = wid - 2 * NF0;
        if (k >= 2 * NF1) return;
        bool stu = k < NF1;
        int jj = stu ? k : k - NF1;
        src = (stu ? sf1 : tf1) + (size_t)jj * 704;    // 16*44
        int b = jj / (NV * 512);
        int r = jj % (NV * 512);
        int v = r >> 9;
        int c = r & 511;
        dst = (stu ? obs : tgt) + ((size_t)(v * NB + b)) * NOBS + 256 + c;
        nvec = 176;               // 704/4
        inv = 1.0f / 704.0f;
    }
    const float4* s4 = (const float4*)src;
    float sum = 0.0f;
    for (int k = lane; k < nvec; k += 64) {
        float4 x = s4[k];
        sum += x.x + x.y + x.z + x.w;
    }
    for (int o = 32; o > 0; o >>= 1) sum += __shfl_down(sum, o);
    if (lane == 0) *dst = sum * inv;
}

// -------- Kernel 2: encoder for all 48 (v,b) rows, 512 threads, split-K --------
__global__ __launch_bounds__(512) void encoder(
    const float* __restrict__ obs,
    const float* __restrict__ w1, const float* __restrict__ b1,
    const float* __restrict__ g, const float* __restrict__ be,
    const float* __restrict__ w2, const float* __restrict__ b2,
    float* __restrict__ obs_embed)
{
    __shared__ float xs[NOBS];
    __shared__ float hs[NH];
    __shared__ float pE[4][NH];
    __shared__ float red[2], red2[2];
    int r = blockIdx.x;       // r = v*NB + b
    int tid = threadIdx.x;    // 0..511
    const float* row = obs + (size_t)r * NOBS;
    for (int i = tid; i < NOBS; i += 512) xs[i] = row[i];
    __syncthreads();

    // layer 1: 128 outs x K=768, 4-way split (192 each)
    {
        int part = tid >> 7, j = tid & 127;
        int k0 = part * 192;
        float a = 0.0f;
        for (int k = k0; k < k0 + 192; k++) a += xs[k] * w1[k * NH + j];
        pE[part][j] = a;
    }
    __syncthreads();

    float a1 = 0.0f;
    if (tid < NH) {
        a1 = b1[tid] + pE[0][tid] + pE[1][tid] + pE[2][tid] + pE[3][tid];
        float v = a1;
        for (int o = 32; o > 0; o >>= 1) v += __shfl_down(v, o);
        if ((tid & 63) == 0) red[tid >> 6] = v;
    }
    __syncthreads();
    if (tid < NH) {
        float mu = (red[0] + red[1]) * (1.0f / 128.0f);
        float d = a1 - mu;
        float dv = d * d;
        for (int o = 32; o > 0; o >>= 1) dv += __shfl_down(dv, o);
        if ((tid & 63) == 0) red2[tid >> 6] = dv;
    }
    __syncthreads();
    if (tid < NH) {
        float mu = (red[0] + red[1]) * (1.0f / 128.0f);
        float var = (red2[0] + red2[1]) * (1.0f / 128.0f);
        float xn = (a1 - mu) * rsqrtf(var + 1e-5f) * g[tid] + be[tid];
        hs[tid] = siluf(xn);
    }
    __syncthreads();

    // layer 2: 128 outs x K=128, 4-way split (32 each)
    {
        int part = tid >> 7, j = tid & 127;
        int k0 = part * 32;
        float a = 0.0f;
        for (int k = k0; k < k0 + 32; k++) a += hs[k] * w2[k * NH + j];
        pE[part][j] = a;
    }
    __syncthreads();
    if (tid < NH) {
        float a = b2[tid] + pE[0][tid] + pE[1][tid] + pE[2][tid] + pE[3][tid];
        obs_embed[(size_t)r * NH + tid] = siluf(a);
    }
}

// -------- Kernel 3: RSSM recurrence, 512 thr, float4 loads, LDS-persist post_w1 --------
// Dynamic LDS layout (floats):
//   pw1   [0,        32768)  : post_w1 256x128, persisted across steps (128 KB)
//   pbuf  [32768,    34816)  : split-K partials, 512 float4 (8 KB)
//   gi_s  [34816,    35200)  : 384
//   deter [35200,    35328)
//   obs_e [35328,    35456)
//   t1    [35456,    35584)
//   t2    [35584,    35712)
//   pmu/plv/qmu/qlv/zsm: 5x32 at [35712, 35872)
constexpr int SMEM_FLOATS = 35872;

__global__ __launch_bounds__(512) void rssm_scan(
    const float* __restrict__ obs_embed,
    const float* __restrict__ maskf,
    const float* __restrict__ eps_prior, const float* __restrict__ eps_post,
    const float* __restrict__ prior_w1, const float* __restrict__ prior_b1,
    const float* __restrict__ prior_w2, const float* __restrict__ prior_b2,
    const float* __restrict__ post_w1, const float* __restrict__ post_b1,
    const float* __restrict__ post_w2, const float* __restrict__ post_b2,
    const float* __restrict__ gru_wih, const float* __restrict__ gru_whh,
    const float* __restrict__ gru_bih, const float* __restrict__ gru_bhh,
    float* __restrict__ deter_all, float* __restrict__ z_all,
    float* __restrict__ kl_out)
{
    extern __shared__ float smem[];
    float* pw1   = smem;
    float* pbuf  = smem + 32768;
    float* gi_s  = smem + 34816;
    float* deter = smem + 35200;
    float* obs_e = smem + 35328;
    float* t1    = smem + 35456;
    float* t2    = smem + 35584;
    float* pmu   = smem + 35712;
    float* plv   = smem + 35744;
    float* qmu   = smem + 35776;
    float* qlv   = smem + 35808;
    float* zsm   = smem + 35840;
    float4* pbuf4 = (float4*)pbuf;
    float4* pw14  = (float4*)pw1;

    int b = blockIdx.x;       // 0..7
    int tid = threadIdx.x;    // 0..511

    // persist post_w1 into LDS (8192 float4)
    {
        const float4* src = (const float4*)post_w1;
        for (int i = tid; i < 8192; i += 512) pw14[i] = src[i];
    }
    if (tid < ND) deter[tid] = 0.0f;
    __syncthreads();

    for (int t = 0; t < NV; t++) {
        int rb = t * NB + b;
        if (tid < NH) obs_e[tid] = obs_embed[(size_t)rb * NH + tid];
        __syncthreads();

        // ---- Phase A partials: prior hidden (waves 0-3) | post hidden (waves 4-7)
        {
            float4 acc = {0.f, 0.f, 0.f, 0.f};
            if (tid < 256) {
                int g = tid & 31, part = tid >> 5;   // 32 groups x 8 parts, K=128
                int k0 = part * 16;
                const float4* w = (const float4*)prior_w1;   // [128][32 f4]
                for (int k = k0; k < k0 + 16; k++) {
                    float x = deter[k];
                    float4 wv = w[k * 32 + g];
                    acc.x += x * wv.x; acc.y += x * wv.y; acc.z += x * wv.z; acc.w += x * wv.w;
                }
                pbuf4[part * 32 + g] = acc;
            } else {
                int u = tid - 256;
                int g = u & 31, part = u >> 5;       // 32 groups x 8 parts, K=256
                int k0 = part * 32;
                for (int k = k0; k < k0 + 32; k++) {
                    float x = (k < ND) ? deter[k] : obs_e[k - ND];
                    float4 wv = pw14[k * 32 + g];    // LDS
                    acc.x += x * wv.x; acc.y += x * wv.y; acc.z += x * wv.z; acc.w += x * wv.w;
                }
                pbuf4[256 + part * 32 + g] = acc;
            }
        }
        __syncthreads();
        if (tid < 256) {
            int j = tid;
            float a = 0.0f;
            if (j < NH) {
                int g = j >> 2, c = j & 3;
                for (int p = 0; p < 8; p++) a += pbuf[(p * 32 + g) * 4 + c];
                t1[j] = siluf(a + prior_b1[j]);
            } else {
                int jj = j - NH;
                int g = jj >> 2, c = jj & 3;
                for (int p = 0; p < 8; p++) a += pbuf[(256 + p * 32 + g) * 4 + c];
                t2[jj] = siluf(a + post_b1[jj]);
            }
        }
        __syncthreads();

        // ---- Phase B partials: prior2 (waves 0-3) | post2 (waves 4-7), K=128
        {
            float4 acc = {0.f, 0.f, 0.f, 0.f};
            if (tid < 256) {
                int g = tid & 15, part = tid >> 4;   // 16 groups x 16 parts
                int k0 = part * 8;
                const float4* w = (const float4*)prior_w2;   // [128][16 f4]
                for (int k = k0; k < k0 + 8; k++) {
                    float x = t1[k];
                    float4 wv = w[k * 16 + g];
                    acc.x += x * wv.x; acc.y += x * wv.y; acc.z += x * wv.z; acc.w += x * wv.w;
                }
                pbuf4[part * 16 + g] = acc;
            } else {
                int u = tid - 256;
                int g = u & 15, part = u >> 4;
                int k0 = part * 8;
                const float4* w = (const float4*)post_w2;
                for (int k = k0; k < k0 + 8; k++) {
                    float x = t2[k];
                    float4 wv = w[k * 16 + g];
                    acc.x += x * wv.x; acc.y += x * wv.y; acc.z += x * wv.z; acc.w += x * wv.w;
                }
                pbuf4[256 + part * 16 + g] = acc;
            }
        }
        __syncthreads();
        if (tid < 128) {
            int j = tid;
            float a = 0.0f;
            if (j < 64) {
                int g = j >> 2, c = j & 3;
                for (int p = 0; p < 16; p++) a += pbuf[(p * 16 + g) * 4 + c];
                a += prior_b2[j];
                if (j < NS) pmu[j] = a; else plv[j - NS] = a;
            } else {
                int jj = j - 64;
                int g = jj >> 2, c = jj & 3;
                for (int p = 0; p < 16; p++) a += pbuf[(256 + p * 16 + g) * 4 + c];
                a += post_b2[jj];
                if (jj < NS) qmu[jj] = a; else qlv[jj - NS] = a;
            }
        }
        __syncthreads();

        // ---- Phase C: z sample + KL
        if (tid < NS) {
            float m = maskf[rb];
            float zp = pmu[tid] + eps_prior[(size_t)rb * NS + tid] * expf(0.5f * plv[tid]);
            float zq = qmu[tid] + eps_post[(size_t)rb * NS + tid] * expf(0.5f * qlv[tid]);
            float z = (m > 0.0f) ? zp : zq;
            zsm[tid] = z;
            z_all[(size_t)rb * NS + tid] = z;
            float vq = fmaxf(expf(qlv[tid]), 1e-5f);
            float vp = fmaxf(expf(plv[tid]), 1e-5f);
            float dm = qmu[tid] - pmu[tid];
            float kle = 0.5f * ((vq + dm * dm) / vp - 1.0f + plv[tid] - qlv[tid]);
            for (int o = 16; o > 0; o >>= 1) kle += __shfl_down(kle, o, 32);
            if (tid == 0) kl_out[rb] = kle;
        }
        __syncthreads();

        // ---- Phase D: gi (threads 0..95, K=32 full) + gh partials (threads 128..511, K=128/4)
        if (tid < 96) {
            int g = tid;   // 96 float4 groups over 384 outs
            float4 acc = {0.f, 0.f, 0.f, 0.f};
            const float4* w = (const float4*)gru_wih;    // [32][96 f4]
            for (int s = 0; s < NS; s++) {
                float x = zsm[s];
                float4 wv = w[s * 96 + g];
                acc.x += x * wv.x; acc.y += x * wv.y; acc.z += x * wv.z; acc.w += x * wv.w;
            }
            gi_s[4 * g + 0] = acc.x + gru_bih[4 * g + 0];
            gi_s[4 * g + 1] = acc.y + gru_bih[4 * g + 1];
            gi_s[4 * g + 2] = acc.z + gru_bih[4 * g + 2];
            gi_s[4 * g + 3] = acc.w + gru_bih[4 * g + 3];
        } else if (tid >= 128) {
            int u = tid - 128;           // 0..383
            int g = u % 96, part = u / 96;   // 96 groups x 4 parts
            int k0 = part * 32;
            float4 acc = {0.f, 0.f, 0.f, 0.f};
            const float4* w = (const float4*)gru_whh;    // [128][96 f4]
            for (int k = k0; k < k0 + 32; k++) {
                float x = deter[k];
                float4 wv = w[k * 96 + g];
                acc.x += x * wv.x; acc.y += x * wv.y; acc.z += x * wv.z; acc.w += x * wv.w;
            }
            pbuf4[part * 96 + g] = acc;
        }
        __syncthreads();

        // ---- Phase E: GRU combine + deter update
        if (tid < ND) {
            int j = tid;
            int gr = j >> 2, c = j & 3;
            float hr = gru_bhh[j], hz = gru_bhh[ND + j], hn = gru_bhh[2 * ND + j];
            for (int p = 0; p < 4; p++) {
                hr += pbuf[(p * 96 + gr) * 4 + c];
                hz += pbuf[(p * 96 + 32 + gr) * 4 + c];
                hn += pbuf[(p * 96 + 64 + gr) * 4 + c];
            }
            float r = sigf(gi_s[j] + hr);
            float u = sigf(gi_s[ND + j] + hz);
            float n = tanhf(gi_s[2 * ND + j] + r * hn);
            float dn = (1.0f - u) * n + u * deter[j];
            deter[j] = dn;
            deter_all[(size_t)rb * ND + j] = dn;
        }
        __syncthreads();
    }
}

// -------- Kernel 4: decoder + recon MSE, 48-way parallel --------
__global__ __launch_bounds__(512) void decoder_kernel(
    const float* __restrict__ deter_all, const float* __restrict__ z_all,
    const float* __restrict__ tgt,
    const float* __restrict__ dec_w1, const float* __restrict__ dec_b1,
    const float* __restrict__ dec_w2, const float* __restrict__ dec_b2,
    float* __restrict__ recon_out)
{
    int rb = blockIdx.x;      // 0..47
    int tid = threadIdx.x;    // 0..511
    __shared__ float din[ND + NS];   // 160
    __shared__ float d1[NH];
    __shared__ float p1[4][NH];
    __shared__ float redb[8];

    if (tid < ND) din[tid] = deter_all[(size_t)rb * ND + tid];
    else if (tid < ND + NS) din[tid] = z_all[(size_t)rb * NS + (tid - ND)];
    __syncthreads();

    // dec layer 1: 128 outs x K=160, 4-way split (40 each)
    {
        int part = tid >> 7, j = tid & 127;
        int k0 = part * 40;
        float a = 0.0f;
        for (int k = k0; k < k0 + 40; k++) a += din[k] * dec_w1[k * NH + j];
        p1[part][j] = a;
    }
    __syncthreads();
    if (tid < NH) {
        float a = dec_b1[tid] + p1[0][tid] + p1[1][tid] + p1[2][tid] + p1[3][tid];
        d1[tid] = siluf(a);
    }
    __syncthreads();

    // dec layer 2 + MSE
    float se = 0.0f;
    const float* trow = tgt + (size_t)rb * NOBS;
    for (int o = tid; o < NOBS; o += 512) {
        float a = dec_b2[o];
        for (int i = 0; i < NH; i++) a += d1[i] * dec_w2[i * NOBS + o];
        float df = a - trow[o];
        se += df * df;
    }
    for (int o = 32; o > 0; o >>= 1) se += __shfl_down(se, o);
    if ((tid & 63) == 0) redb[tid >> 6] = se;
    __syncthreads();
    if (tid == 0) {
        float s = 0.0f;
        for (int p = 0; p < 8; p++) s += redb[p];
        recon_out[rb] = s * (1.0f / 768.0f);
    }
}

// -------- Kernel 5: finalize (mask-weighted scalar combine) --------
__global__ void finalize(const float* __restrict__ maskf,
                         const float* __restrict__ recon,
                         const float* __restrict__ kl,
                         float* __restrict__ out)
{
    if (threadIdx.x != 0 || blockIdx.x != 0) return;
    float rl = 0.0f, rs = 0.0f, ka = 0.0f, kn = 0.0f;
    for (int t = 0; t < NV; t++) {
        float ms = 0.0f, rsum = 0.0f, osum = 0.0f, ksum = 0.0f;
        for (int b = 0; b < NB; b++) {
            float m = maskf[t * NB + b];
            ms += m;
            rsum += recon[t * NB + b] * m;
            osum += 1.0f - m;
            ksum += kl[t * NB + b] * (1.0f - m);
        }
        if (ms > 0.0f) { rl += rsum / fmaxf(ms, 1.0f); rs += 1.0f; }
        if (osum > 0.0f) { ka += ksum / fmaxf(osum, 1.0f); kn += 1.0f; }
    }
    out[0] = rl / fmaxf(rs, 1.0f);
    out[1] = (ka / fmaxf(kn, 1.0f)) * 1e-4f;
}

extern "C" void kernel_launch(void* const* d_in, const int* in_sizes, int n_in,
                              void* d_out, int out_size, void* d_ws, size_t ws_size,
                              hipStream_t stream) {
    const float* sf0 = (const float*)d_in[0];
    const float* sf1 = (const float*)d_in[1];
    const float* tf0 = (const float*)d_in[2];
    const float* tf1 = (const float*)d_in[3];
    const void*  cam = d_in[4];
    const float* eps_prior = (const float*)d_in[5];
    const float* eps_post  = (const float*)d_in[6];
    const float* enc_w1 = (const float*)d_in[7];
    const float* enc_b1 = (const float*)d_in[8];
    const float* ln_g   = (const float*)d_in[9];
    const float* ln_b   = (const float*)d_in[10];
    const float* enc_w2 = (const float*)d_in[11];
    const float* enc_b2 = (const float*)d_in[12];
    const float* prior_w1 = (const float*)d_in[13];
    const float* prior_b1 = (const float*)d_in[14];
    const float* prior_w2 = (const float*)d_in[15];
    const float* prior_b2 = (const float*)d_in[16];
    const float* post_w1 = (const float*)d_in[17];
    const float* post_b1 = (const float*)d_in[18];
    const float* post_w2 = (const float*)d_in[19];
    const float* post_b2 = (const float*)d_in[20];
    const float* dec_w1 = (const float*)d_in[21];
    const float* dec_b1 = (const float*)d_in[22];
    const float* dec_w2 = (const float*)d_in[23];
    const float* dec_b2 = (const float*)d_in[24];
    const float* gru_wih = (const float*)d_in[25];
    const float* gru_whh = (const float*)d_in[26];
    const float* gru_bih = (const float*)d_in[27];
    const float* gru_bhh = (const float*)d_in[28];

    float* ws = (float*)d_ws;
    float* obs   = ws;                 // 48*768 = 36864
    float* tgt   = ws + 36864;         // 36864
    float* oe    = ws + 73728;         // 48*128 = 6144
    float* maskf = ws + 79872;         // 48
    float* rec   = ws + 79920;         // 48
    float* klv   = ws + 79968;         // 48
    float* deter_all = ws + 80016;     // 48*128 = 6144
    float* z_all     = ws + 86160;     // 48*32  = 1536

    prep_mask<<<1, 64, 0, stream>>>(cam, maskf);
    reduce_feats<<<18432, 256, 0, stream>>>(sf0, sf1, tf0, tf1, obs, tgt);
    encoder<<<48, 512, 0, stream>>>(obs, enc_w1, enc_b1, ln_g, ln_b, enc_w2, enc_b2, oe);
    rssm_scan<<<8, 512, SMEM_FLOATS * sizeof(float), stream>>>(
                                      oe, maskf, eps_prior, eps_post,
                                      prior_w1, prior_b1, prior_w2, prior_b2,
                                      post_w1, post_b1, post_w2, post_b2,
                                      gru_wih, gru_whh, gru_bih, gru_bhh,
                                      deter_all, z_all, klv);
    decoder_kernel<<<48, 512, 0, stream>>>(deter_all, z_all, tgt,
                                           dec_w1, dec_b1, dec_w2, dec_b2, rec);
    finalize<<<1, 64, 0, stream>>>(maskf, rec, klv, (float*)d_out);
}

// Round 4
// 149.162 us; speedup vs baseline: 2.9977x; 1.6939x over previous
//
#include <hip/hip_runtime.h>
#include <cstddef>

// Problem constants
constexpr int NB = 8;      // batch
constexpr int NV = 6;      // views (scan length)
constexpr int NS = 32;     // stochastic dim S
constexpr int ND = 128;    // deter dim D
constexpr int NH = 128;    // hidden H
constexpr int NOBS = 768;  // obs dim

__device__ __forceinline__ float sigf(float x) { return 1.0f / (1.0f + expf(-x)); }
__device__ __forceinline__ float siluf(float x) { return x / (1.0f + expf(-x)); }

// -------- Kernel 0: mask prep (detect int32 vs byte bool layout) --------
__global__ void prep_mask(const void* cam, float* maskf) {
    if (threadIdx.x != 0 || blockIdx.x != 0) return;
    const int* wi = (const int*)cam;
    bool is_i32 = true;
    for (int i = 0; i < NB * NV; i++) {
        unsigned v = (unsigned)wi[i];
        if (v > 1u) { is_i32 = false; break; }
    }
    const unsigned char* wb = (const unsigned char*)cam;
    for (int b = 0; b < NB; b++)
        for (int v = 0; v < NV; v++) {
            int val = is_i32 ? wi[b * NV + v] : (int)wb[b * NV + v];
            maskf[v * NB + b] = val ? 1.0f : 0.0f;   // mask_T layout (V,B)
        }
}

// -------- shared reducer job: one 64-lane wave per channel --------
// jobs [0,12288): f0 channels (2816 floats each -> 11 float4/lane)
// jobs [12288,36864): f1 channels (704 floats -> 2.75 float4/lane)
__device__ __forceinline__ void reduce_job(int wid, int lane,
    const float* __restrict__ f0, const float* __restrict__ f1,
    float* __restrict__ out)
{
    if (wid < 12288) {
        const float4* s4 = (const float4*)(f0 + (size_t)wid * 2816);
        float s = 0.f;
        #pragma unroll
        for (int it = 0; it < 11; it++) {
            float4 x = s4[lane + it * 64];
            s += x.x + x.y + x.z + x.w;
        }
        for (int o = 32; o > 0; o >>= 1) s += __shfl_down(s, o);
        if (lane == 0) {
            int b = wid / 1536, r = wid % 1536, v = r >> 8, c = r & 255;
            out[(size_t)(v * NB + b) * NOBS + c] = s * (1.0f / 2816.0f);
        }
    } else {
        int jj = wid - 12288;
        if (jj >= 24576) return;
        const float4* s4 = (const float4*)(f1 + (size_t)jj * 704);
        float4 x0 = s4[lane];
        float4 x1 = s4[lane + 64];
        float s = x0.x + x0.y + x0.z + x0.w + x1.x + x1.y + x1.z + x1.w;
        if (lane < 48) {
            float4 x2 = s4[lane + 128];
            s += x2.x + x2.y + x2.z + x2.w;
        }
        for (int o = 32; o > 0; o >>= 1) s += __shfl_down(s, o);
        if (lane == 0) {
            int b = jj / 3072, r = jj % 3072, v = r >> 9, c = r & 511;
            out[(size_t)(v * NB + b) * NOBS + 256 + c] = s * (1.0f / 704.0f);
        }
    }
}

// -------- Kernel 1: student feature means (produces obs) --------
__global__ __launch_bounds__(512) void reduce_obs(
    const float* __restrict__ sf0, const float* __restrict__ sf1,
    float* __restrict__ obs)
{
    int wid = blockIdx.x * 8 + (threadIdx.x >> 6);
    reduce_job(wid, threadIdx.x & 63, sf0, sf1, obs);
}

// -------- Kernel 2: encoder for all 48 (v,b) rows, 512 threads, split-K --------
__global__ __launch_bounds__(512) void encoder(
    const float* __restrict__ obs,
    const float* __restrict__ w1, const float* __restrict__ b1,
    const float* __restrict__ g, const float* __restrict__ be,
    const float* __restrict__ w2, const float* __restrict__ b2,
    float* __restrict__ obs_embed)
{
    __shared__ float xs[NOBS];
    __shared__ float hs[NH];
    __shared__ float pE[4][NH];
    __shared__ float red[2], red2[2];
    int r = blockIdx.x;       // r = v*NB + b
    int tid = threadIdx.x;    // 0..511
    const float* row = obs + (size_t)r * NOBS;
    for (int i = tid; i < NOBS; i += 512) xs[i] = row[i];
    __syncthreads();

    // layer 1: 128 outs x K=768, 4-way split (192 each)
    {
        int part = tid >> 7, j = tid & 127;
        int k0 = part * 192;
        float a = 0.0f;
        #pragma unroll 8
        for (int k = k0; k < k0 + 192; k++) a += xs[k] * w1[k * NH + j];
        pE[part][j] = a;
    }
    __syncthreads();

    float a1 = 0.0f;
    if (tid < NH) {
        a1 = b1[tid] + pE[0][tid] + pE[1][tid] + pE[2][tid] + pE[3][tid];
        float v = a1;
        for (int o = 32; o > 0; o >>= 1) v += __shfl_down(v, o);
        if ((tid & 63) == 0) red[tid >> 6] = v;
    }
    __syncthreads();
    if (tid < NH) {
        float mu = (red[0] + red[1]) * (1.0f / 128.0f);
        float d = a1 - mu;
        float dv = d * d;
        for (int o = 32; o > 0; o >>= 1) dv += __shfl_down(dv, o);
        if ((tid & 63) == 0) red2[tid >> 6] = dv;
    }
    __syncthreads();
    if (tid < NH) {
        float mu = (red[0] + red[1]) * (1.0f / 128.0f);
        float var = (red2[0] + red2[1]) * (1.0f / 128.0f);
        float xn = (a1 - mu) * rsqrtf(var + 1e-5f) * g[tid] + be[tid];
        hs[tid] = siluf(xn);
    }
    __syncthreads();

    // layer 2: 128 outs x K=128, 4-way split (32 each)
    {
        int part = tid >> 7, j = tid & 127;
        int k0 = part * 32;
        float a = 0.0f;
        #pragma unroll 8
        for (int k = k0; k < k0 + 32; k++) a += hs[k] * w2[k * NH + j];
        pE[part][j] = a;
    }
    __syncthreads();
    if (tid < NH) {
        float a = b2[tid] + pE[0][tid] + pE[1][tid] + pE[2][tid] + pE[3][tid];
        obs_embed[(size_t)r * NH + tid] = siluf(a);
    }
}

// -------- Kernel 3: fused RSSM scan (blocks 0-7) + teacher reduce (blocks 8+) --------
// Dynamic LDS layout (floats):
//   pw1   [0,        32768)  : post_w1 256x128, persisted across steps (128 KB)
//   pbuf  [32768,    34816)  : split-K partials, 512 float4 (8 KB)
//   gi_s  [34816,    35200)  : 384
//   deter [35200,    35328)
//   obs_e [35328,    35456)
//   t1    [35456,    35584)
//   t2    [35584,    35712)
//   pmu/plv/qmu/qlv/zsm: 5x32 at [35712, 35872)
constexpr int SMEM_FLOATS = 35872;

__global__ __launch_bounds__(512) void fused_scan_tgt(
    const float* __restrict__ obs_embed,
    const float* __restrict__ maskf,
    const float* __restrict__ eps_prior, const float* __restrict__ eps_post,
    const float* __restrict__ prior_w1, const float* __restrict__ prior_b1,
    const float* __restrict__ prior_w2, const float* __restrict__ prior_b2,
    const float* __restrict__ post_w1, const float* __restrict__ post_b1,
    const float* __restrict__ post_w2, const float* __restrict__ post_b2,
    const float* __restrict__ gru_wih, const float* __restrict__ gru_whh,
    const float* __restrict__ gru_bih, const float* __restrict__ gru_bhh,
    float* __restrict__ deter_all, float* __restrict__ z_all,
    float* __restrict__ kl_out,
    const float* __restrict__ tf0, const float* __restrict__ tf1,
    float* __restrict__ tgt)
{
    extern __shared__ float smem[];

    if (blockIdx.x >= 8) {
        // ---- teacher-feature reduction path (runs concurrently with the scan)
        int wid = (blockIdx.x - 8) * 8 + (threadIdx.x >> 6);
        reduce_job(wid, threadIdx.x & 63, tf0, tf1, tgt);
        return;
    }

    float* pw1   = smem;
    float* pbuf  = smem + 32768;
    float* gi_s  = smem + 34816;
    float* deter = smem + 35200;
    float* obs_e = smem + 35328;
    float* t1    = smem + 35456;
    float* t2    = smem + 35584;
    float* pmu   = smem + 35712;
    float* plv   = smem + 35744;
    float* qmu   = smem + 35776;
    float* qlv   = smem + 35808;
    float* zsm   = smem + 35840;
    float4* pbuf4 = (float4*)pbuf;
    float4* pw14  = (float4*)pw1;

    int b = blockIdx.x;       // 0..7
    int tid = threadIdx.x;    // 0..511

    // persist post_w1 into LDS (8192 float4)
    {
        const float4* src = (const float4*)post_w1;
        #pragma unroll 4
        for (int i = tid; i < 8192; i += 512) pw14[i] = src[i];
    }
    if (tid < ND) deter[tid] = 0.0f;
    __syncthreads();

    for (int t = 0; t < NV; t++) {
        int rb = t * NB + b;
        if (tid < NH) obs_e[tid] = obs_embed[(size_t)rb * NH + tid];
        __syncthreads();

        // ---- Phase A partials: prior hidden (waves 0-3) | post hidden (waves 4-7)
        {
            float4 acc = {0.f, 0.f, 0.f, 0.f};
            if (tid < 256) {
                int g = tid & 31, part = tid >> 5;   // 32 groups x 8 parts, K=128
                int k0 = part * 16;
                const float4* w = (const float4*)prior_w1;   // [128][32 f4]
                #pragma unroll 4
                for (int k = k0; k < k0 + 16; k++) {
                    float x = deter[k];
                    float4 wv = w[k * 32 + g];
                    acc.x += x * wv.x; acc.y += x * wv.y; acc.z += x * wv.z; acc.w += x * wv.w;
                }
                pbuf4[part * 32 + g] = acc;
            } else {
                int u = tid - 256;
                int g = u & 31, part = u >> 5;       // 32 groups x 8 parts, K=256
                int k0 = part * 32;
                #pragma unroll 4
                for (int k = k0; k < k0 + 32; k++) {
                    float x = (k < ND) ? deter[k] : obs_e[k - ND];
                    float4 wv = pw14[k * 32 + g];    // LDS
                    acc.x += x * wv.x; acc.y += x * wv.y; acc.z += x * wv.z; acc.w += x * wv.w;
                }
                pbuf4[256 + part * 32 + g] = acc;
            }
        }
        __syncthreads();
        if (tid < 256) {
            int j = tid;
            float a = 0.0f;
            if (j < NH) {
                int g = j >> 2, c = j & 3;
                #pragma unroll
                for (int p = 0; p < 8; p++) a += pbuf[(p * 32 + g) * 4 + c];
                t1[j] = siluf(a + prior_b1[j]);
            } else {
                int jj = j - NH;
                int g = jj >> 2, c = jj & 3;
                #pragma unroll
                for (int p = 0; p < 8; p++) a += pbuf[(256 + p * 32 + g) * 4 + c];
                t2[jj] = siluf(a + post_b1[jj]);
            }
        }
        __syncthreads();

        // ---- Phase B partials: prior2 (waves 0-3) | post2 (waves 4-7), K=128
        {
            float4 acc = {0.f, 0.f, 0.f, 0.f};
            if (tid < 256) {
                int g = tid & 15, part = tid >> 4;   // 16 groups x 16 parts
                int k0 = part * 8;
                const float4* w = (const float4*)prior_w2;   // [128][16 f4]
                #pragma unroll 4
                for (int k = k0; k < k0 + 8; k++) {
                    float x = t1[k];
                    float4 wv = w[k * 16 + g];
                    acc.x += x * wv.x; acc.y += x * wv.y; acc.z += x * wv.z; acc.w += x * wv.w;
                }
                pbuf4[part * 16 + g] = acc;
            } else {
                int u = tid - 256;
                int g = u & 15, part = u >> 4;
                int k0 = part * 8;
                const float4* w = (const float4*)post_w2;
                #pragma unroll 4
                for (int k = k0; k < k0 + 8; k++) {
                    float x = t2[k];
                    float4 wv = w[k * 16 + g];
                    acc.x += x * wv.x; acc.y += x * wv.y; acc.z += x * wv.z; acc.w += x * wv.w;
                }
                pbuf4[256 + part * 16 + g] = acc;
            }
        }
        __syncthreads();
        if (tid < 128) {
            int j = tid;
            float a = 0.0f;
            if (j < 64) {
                int g = j >> 2, c = j & 3;
                #pragma unroll
                for (int p = 0; p < 16; p++) a += pbuf[(p * 16 + g) * 4 + c];
                a += prior_b2[j];
                if (j < NS) pmu[j] = a; else plv[j - NS] = a;
            } else {
                int jj = j - 64;
                int g = jj >> 2, c = jj & 3;
                #pragma unroll
                for (int p = 0; p < 16; p++) a += pbuf[(256 + p * 16 + g) * 4 + c];
                a += post_b2[jj];
                if (jj < NS) qmu[jj] = a; else qlv[jj - NS] = a;
            }
        }
        __syncthreads();

        // ---- Phase C: z sample + KL
        if (tid < NS) {
            float m = maskf[rb];
            float zp = pmu[tid] + eps_prior[(size_t)rb * NS + tid] * expf(0.5f * plv[tid]);
            float zq = qmu[tid] + eps_post[(size_t)rb * NS + tid] * expf(0.5f * qlv[tid]);
            float z = (m > 0.0f) ? zp : zq;
            zsm[tid] = z;
            z_all[(size_t)rb * NS + tid] = z;
            float vq = fmaxf(expf(qlv[tid]), 1e-5f);
            float vp = fmaxf(expf(plv[tid]), 1e-5f);
            float dm = qmu[tid] - pmu[tid];
            float kle = 0.5f * ((vq + dm * dm) / vp - 1.0f + plv[tid] - qlv[tid]);
            for (int o = 16; o > 0; o >>= 1) kle += __shfl_down(kle, o, 32);
            if (tid == 0) kl_out[rb] = kle;
        }
        __syncthreads();

        // ---- Phase D: gi (threads 0..95, K=32 full) + gh partials (threads 128..511, K=128/4)
        if (tid < 96) {
            int g = tid;   // 96 float4 groups over 384 outs
            float4 acc = {0.f, 0.f, 0.f, 0.f};
            const float4* w = (const float4*)gru_wih;    // [32][96 f4]
            #pragma unroll 4
            for (int s = 0; s < NS; s++) {
                float x = zsm[s];
                float4 wv = w[s * 96 + g];
                acc.x += x * wv.x; acc.y += x * wv.y; acc.z += x * wv.z; acc.w += x * wv.w;
            }
            gi_s[4 * g + 0] = acc.x + gru_bih[4 * g + 0];
            gi_s[4 * g + 1] = acc.y + gru_bih[4 * g + 1];
            gi_s[4 * g + 2] = acc.z + gru_bih[4 * g + 2];
            gi_s[4 * g + 3] = acc.w + gru_bih[4 * g + 3];
        } else if (tid >= 128) {
            int u = tid - 128;           // 0..383
            int g = u % 96, part = u / 96;   // 96 groups x 4 parts
            int k0 = part * 32;
            float4 acc = {0.f, 0.f, 0.f, 0.f};
            const float4* w = (const float4*)gru_whh;    // [128][96 f4]
            #pragma unroll 4
            for (int k = k0; k < k0 + 32; k++) {
                float x = deter[k];
                float4 wv = w[k * 96 + g];
                acc.x += x * wv.x; acc.y += x * wv.y; acc.z += x * wv.z; acc.w += x * wv.w;
            }
            pbuf4[part * 96 + g] = acc;
        }
        __syncthreads();

        // ---- Phase E: GRU combine + deter update
        if (tid < ND) {
            int j = tid;
            int gr = j >> 2, c = j & 3;
            float hr = gru_bhh[j], hz = gru_bhh[ND + j], hn = gru_bhh[2 * ND + j];
            #pragma unroll
            for (int p = 0; p < 4; p++) {
                hr += pbuf[(p * 96 + gr) * 4 + c];
                hz += pbuf[(p * 96 + 32 + gr) * 4 + c];
                hn += pbuf[(p * 96 + 64 + gr) * 4 + c];
            }
            float r = sigf(gi_s[j] + hr);
            float u = sigf(gi_s[ND + j] + hz);
            float n = tanhf(gi_s[2 * ND + j] + r * hn);
            float dn = (1.0f - u) * n + u * deter[j];
            deter[j] = dn;
            deter_all[(size_t)rb * ND + j] = dn;
        }
        __syncthreads();
    }
}

// -------- Kernel 4: decoder + recon MSE, 48-way parallel --------
__global__ __launch_bounds__(512) void decoder_kernel(
    const float* __restrict__ deter_all, const float* __restrict__ z_all,
    const float* __restrict__ tgt,
    const float* __restrict__ dec_w1, const float* __restrict__ dec_b1,
    const float* __restrict__ dec_w2, const float* __restrict__ dec_b2,
    float* __restrict__ recon_out)
{
    int rb = blockIdx.x;      // 0..47
    int tid = threadIdx.x;    // 0..511
    __shared__ float din[ND + NS];   // 160
    __shared__ float d1[NH];
    __shared__ float p1[4][NH];
    __shared__ float redb[8];

    if (tid < ND) din[tid] = deter_all[(size_t)rb * ND + tid];
    else if (tid < ND + NS) din[tid] = z_all[(size_t)rb * NS + (tid - ND)];
    __syncthreads();

    // dec layer 1: 128 outs x K=160, 4-way split (40 each)
    {
        int part = tid >> 7, j = tid & 127;
        int k0 = part * 40;
        float a = 0.0f;
        #pragma unroll 8
        for (int k = k0; k < k0 + 40; k++) a += din[k] * dec_w1[k * NH + j];
        p1[part][j] = a;
    }
    __syncthreads();
    if (tid < NH) {
        float a = dec_b1[tid] + p1[0][tid] + p1[1][tid] + p1[2][tid] + p1[3][tid];
        d1[tid] = siluf(a);
    }
    __syncthreads();

    // dec layer 2 + MSE
    float se = 0.0f;
    const float* trow = tgt + (size_t)rb * NOBS;
    for (int o = tid; o < NOBS; o += 512) {
        float a = dec_b2[o];
        #pragma unroll 8
        for (int i = 0; i < NH; i++) a += d1[i] * dec_w2[i * NOBS + o];
        float df = a - trow[o];
        se += df * df;
    }
    for (int o = 32; o > 0; o >>= 1) se += __shfl_down(se, o);
    if ((tid & 63) == 0) redb[tid >> 6] = se;
    __syncthreads();
    if (tid == 0) {
        float s = 0.0f;
        for (int p = 0; p < 8; p++) s += redb[p];
        recon_out[rb] = s * (1.0f / 768.0f);
    }
}

// -------- Kernel 5: finalize (mask-weighted scalar combine) --------
__global__ void finalize(const float* __restrict__ maskf,
                         const float* __restrict__ recon,
                         const float* __restrict__ kl,
                         float* __restrict__ out)
{
    if (threadIdx.x != 0 || blockIdx.x != 0) return;
    float rl = 0.0f, rs = 0.0f, ka = 0.0f, kn = 0.0f;
    for (int t = 0; t < NV; t++) {
        float ms = 0.0f, rsum = 0.0f, osum = 0.0f, ksum = 0.0f;
        for (int b = 0; b < NB; b++) {
            float m = maskf[t * NB + b];
            ms += m;
            rsum += recon[t * NB + b] * m;
            osum += 1.0f - m;
            ksum += kl[t * NB + b] * (1.0f - m);
        }
        if (ms > 0.0f) { rl += rsum / fmaxf(ms, 1.0f); rs += 1.0f; }
        if (osum > 0.0f) { ka += ksum / fmaxf(osum, 1.0f); kn += 1.0f; }
    }
    out[0] = rl / fmaxf(rs, 1.0f);
    out[1] = (ka / fmaxf(kn, 1.0f)) * 1e-4f;
}

extern "C" void kernel_launch(void* const* d_in, const int* in_sizes, int n_in,
                              void* d_out, int out_size, void* d_ws, size_t ws_size,
                              hipStream_t stream) {
    const float* sf0 = (const float*)d_in[0];
    const float* sf1 = (const float*)d_in[1];
    const float* tf0 = (const float*)d_in[2];
    const float* tf1 = (const float*)d_in[3];
    const void*  cam = d_in[4];
    const float* eps_prior = (const float*)d_in[5];
    const float* eps_post  = (const float*)d_in[6];
    const float* enc_w1 = (const float*)d_in[7];
    const float* enc_b1 = (const float*)d_in[8];
    const float* ln_g   = (const float*)d_in[9];
    const float* ln_b   = (const float*)d_in[10];
    const float* enc_w2 = (const float*)d_in[11];
    const float* enc_b2 = (const float*)d_in[12];
    const float* prior_w1 = (const float*)d_in[13];
    const float* prior_b1 = (const float*)d_in[14];
    const float* prior_w2 = (const float*)d_in[15];
    const float* prior_b2 = (const float*)d_in[16];
    const float* post_w1 = (const float*)d_in[17];
    const float* post_b1 = (const float*)d_in[18];
    const float* post_w2 = (const float*)d_in[19];
    const float* post_b2 = (const float*)d_in[20];
    const float* dec_w1 = (const float*)d_in[21];
    const float* dec_b1 = (const float*)d_in[22];
    const float* dec_w2 = (const float*)d_in[23];
    const float* dec_b2 = (const float*)d_in[24];
    const float* gru_wih = (const float*)d_in[25];
    const float* gru_whh = (const float*)d_in[26];
    const float* gru_bih = (const float*)d_in[27];
    const float* gru_bhh = (const float*)d_in[28];

    float* ws = (float*)d_ws;
    float* obs   = ws;                 // 48*768 = 36864
    float* tgt   = ws + 36864;         // 36864
    float* oe    = ws + 73728;         // 48*128 = 6144
    float* maskf = ws + 79872;         // 48
    float* rec   = ws + 79920;         // 48
    float* klv   = ws + 79968;         // 48
    float* deter_all = ws + 80016;     // 48*128 = 6144
    float* z_all     = ws + 86160;     // 48*32  = 1536

    prep_mask<<<1, 64, 0, stream>>>(cam, maskf);
    // student reduction: 36864 wave-jobs, 8 waves/block -> 4608 blocks
    reduce_obs<<<4608, 512, 0, stream>>>(sf0, sf1, obs);
    encoder<<<48, 512, 0, stream>>>(obs, enc_w1, enc_b1, ln_g, ln_b, enc_w2, enc_b2, oe);
    // fused: blocks 0-7 scan, blocks 8..4615 teacher reduction (36864 jobs)
    fused_scan_tgt<<<8 + 4608, 512, SMEM_FLOATS * sizeof(float), stream>>>(
                                      oe, maskf, eps_prior, eps_post,
                                      prior_w1, prior_b1, prior_w2, prior_b2,
                                      post_w1, post_b1, post_w2, post_b2,
                                      gru_wih, gru_whh, gru_bih, gru_bhh,
                                      deter_all, z_all, klv,
                                      tf0, tf1, tgt);
    decoder_kernel<<<48, 512, 0, stream>>>(deter_all, z_all, tgt,
                                           dec_w1, dec_b1, dec_w2, dec_b2, rec);
    finalize<<<1, 64, 0, stream>>>(maskf, rec, klv, (float*)d_out);
}